// Round 1
// baseline (160.313 us; speedup 1.0000x reference)
//
#include <hip/hip_runtime.h>
#include <stdint.h>

#define N 2048
#define TILE 128
#define BK 32

typedef unsigned short u16;
typedef __bf16 bf16x8 __attribute__((ext_vector_type(8)));
typedef unsigned short ushortx8 __attribute__((ext_vector_type(8)));
typedef float floatx4 __attribute__((ext_vector_type(4)));

static __device__ __forceinline__ u16 f2bf(float f) {
  unsigned int u = __builtin_bit_cast(unsigned int, f);
  return (u16)((u + 0x7fffu + ((u >> 16) & 1u)) >> 16);  // RNE, inputs finite
}
static __device__ __forceinline__ float bf2f(u16 h) {
  unsigned int u = ((unsigned int)h) << 16;
  return __builtin_bit_cast(float, u);
}

// async global->LDS, 16B per lane. LDS dest must be wave-uniform base + lane*16.
static __device__ __forceinline__ void cp16(u16* lds, const u16* g) {
  __builtin_amdgcn_global_load_lds((const __attribute__((address_space(1))) void*)g,
                                   (__attribute__((address_space(3))) void*)lds,
                                   16, 0, 0);
}

// ---------------------------------------------------------------------------
// cast + transpose: Ab[r][c] = bf16(A[r][c]); Abt[c][r] = bf16(A[r][c])
// block (32,8), grid (64,64)
// ---------------------------------------------------------------------------
__global__ void cast_tr(const float* __restrict__ A, u16* __restrict__ Ab,
                        u16* __restrict__ Abt) {
  __shared__ float tile[32][33];
  const int tx = threadIdx.x, ty = threadIdx.y;
  const int c = blockIdx.x * 32 + tx;
#pragma unroll
  for (int i = 0; i < 4; i++) {
    const int r = blockIdx.y * 32 + ty + i * 8;
    const float v = A[r * N + c];
    Ab[r * N + c] = f2bf(v);
    tile[ty + i * 8][tx] = v;
  }
  __syncthreads();
  const int r2 = blockIdx.y * 32 + tx;  // Abt minor index (original row)
#pragma unroll
  for (int i = 0; i < 4; i++) {
    const int c2 = blockIdx.x * 32 + ty + i * 8;  // Abt major index (original col)
    Abt[c2 * N + r2] = f2bf(tile[tx][ty + i * 8]);
  }
}

// ---------------------------------------------------------------------------
// GEMM core: C_tile += L[128 x K] * R[K x 128], with Rt in [n][k] layout.
// 256 threads = 4 waves in 2x2; each wave owns a 64x64 subtile = 4x4 MFMAs.
// m97 structure: global_load_lds width 16, 2-barrier K-loop, BK=32.
// ---------------------------------------------------------------------------
__device__ __forceinline__ void gemm_tile(const u16* __restrict__ L,
                                          const u16* __restrict__ Rt,
                                          floatx4 acc[4][4]) {
  __shared__ __align__(16) u16 As[TILE * BK];
  __shared__ __align__(16) u16 Bs[TILE * BK];

  const int t = threadIdx.x;
  const int row0 = blockIdx.y * TILE;
  const int col0 = blockIdx.x * TILE;

  // staging: thread t covers 16B chunk t and t+256 of each 128x32 tile
  const int crow = t >> 2;            // 0..63
  const int coff = (t & 3) * 8;       // element offset within a 32-wide row
  const u16* gA0 = L + (size_t)(row0 + crow) * N + coff;
  const u16* gA1 = gA0 + (size_t)64 * N;
  const u16* gB0 = Rt + (size_t)(col0 + crow) * N + coff;
  const u16* gB1 = gB0 + (size_t)64 * N;
  u16* lA0 = As + t * 8;
  u16* lA1 = As + 2048 + t * 8;
  u16* lB0 = Bs + t * 8;
  u16* lB1 = Bs + 2048 + t * 8;

  const int lane = t & 63;
  const int w = t >> 6;
  const int wr = (w >> 1) * 64;
  const int wc = (w & 1) * 64;
  const int lr = lane & 15;           // frag m/n index; also C col
  const int q = lane >> 4;            // frag k-group; C row group

#pragma unroll
  for (int i = 0; i < 4; i++)
#pragma unroll
    for (int j = 0; j < 4; j++) acc[i][j] = (floatx4){0.f, 0.f, 0.f, 0.f};

  for (int k0 = 0; k0 < N; k0 += BK) {
    cp16(lA0, gA0 + k0);
    cp16(lA1, gA1 + k0);
    cp16(lB0, gB0 + k0);
    cp16(lB1, gB1 + k0);
    __syncthreads();  // drains vmcnt for the global_load_lds batch

    bf16x8 a[4], b[4];
#pragma unroll
    for (int mt = 0; mt < 4; mt++)
      a[mt] = __builtin_bit_cast(
          bf16x8, *(const ushortx8*)&As[(wr + mt * 16 + lr) * BK + q * 8]);
#pragma unroll
    for (int nt = 0; nt < 4; nt++)
      b[nt] = __builtin_bit_cast(
          bf16x8, *(const ushortx8*)&Bs[(wc + nt * 16 + lr) * BK + q * 8]);
#pragma unroll
    for (int mt = 0; mt < 4; mt++)
#pragma unroll
      for (int nt = 0; nt < 4; nt++)
        acc[mt][nt] = __builtin_amdgcn_mfma_f32_16x16x32_bf16(
            a[mt], b[nt], acc[mt][nt], 0, 0, 0);
    __syncthreads();  // protect LDS from next iteration's staging
  }
}

// GEMM1: Mb = bf16(A @ A)
__global__ __launch_bounds__(256, 2) void gemm_aa(const u16* __restrict__ Ab,
                                                  const u16* __restrict__ Abt,
                                                  u16* __restrict__ Mb) {
  floatx4 acc[4][4];
  gemm_tile(Ab, Abt, acc);
  const int t = threadIdx.x;
  const int lane = t & 63, w = t >> 6;
  const int wr = (w >> 1) * 64, wc = (w & 1) * 64;
  const int lr = lane & 15, q = lane >> 4;
  const int row0 = blockIdx.y * TILE, col0 = blockIdx.x * TILE;
#pragma unroll
  for (int mt = 0; mt < 4; mt++)
#pragma unroll
    for (int r = 0; r < 4; r++) {
      const int rr = row0 + wr + mt * 16 + q * 4 + r;
#pragma unroll
      for (int nt = 0; nt < 4; nt++) {
        const int cc = col0 + wc + nt * 16 + lr;
        Mb[(size_t)rr * N + cc] = f2bf(acc[mt][nt][r]);
      }
    }
}

// rdeg[i] = 1 / (4*rowsum(M)_i + 1)   (with reference's <=1e-10 guard)
__global__ void rowsum_k(const u16* __restrict__ Mb, float* __restrict__ rdeg) {
  const int row = blockIdx.x;
  const int t = threadIdx.x;
  const ushortx8 v = *((const ushortx8*)(Mb + (size_t)row * N) + t);
  float s = 0.f;
#pragma unroll
  for (int j = 0; j < 8; j++) s += bf2f(v[j]);
#pragma unroll
  for (int off = 32; off > 0; off >>= 1) s += __shfl_down(s, off, 64);
  __shared__ float ws[4];
  if ((t & 63) == 0) ws[t >> 6] = s;
  __syncthreads();
  if (t == 0) {
    float d = 4.f * (ws[0] + ws[1] + ws[2] + ws[3]) + 1.f;
    if (d <= 1e-10f) d = 1.f;
    rdeg[row] = 1.f / d;
  }
}

// GEMM2 + fused norm epilogue: out = (8*(M@A) + 2*A) * rdeg[row]
__global__ __launch_bounds__(256, 2) void gemm_ma(const u16* __restrict__ Mb,
                                                  const u16* __restrict__ Abt,
                                                  const float* __restrict__ A,
                                                  const float* __restrict__ rdeg,
                                                  float* __restrict__ out) {
  floatx4 acc[4][4];
  gemm_tile(Mb, Abt, acc);
  const int t = threadIdx.x;
  const int lane = t & 63, w = t >> 6;
  const int wr = (w >> 1) * 64, wc = (w & 1) * 64;
  const int lr = lane & 15, q = lane >> 4;
  const int row0 = blockIdx.y * TILE, col0 = blockIdx.x * TILE;
#pragma unroll
  for (int mt = 0; mt < 4; mt++)
#pragma unroll
    for (int r = 0; r < 4; r++) {
      const int rr = row0 + wr + mt * 16 + q * 4 + r;
      const float rd = rdeg[rr];
#pragma unroll
      for (int nt = 0; nt < 4; nt++) {
        const int cc = col0 + wc + nt * 16 + lr;
        out[(size_t)rr * N + cc] =
            (8.f * acc[mt][nt][r] + 2.f * A[(size_t)rr * N + cc]) * rd;
      }
    }
}

extern "C" void kernel_launch(void* const* d_in, const int* in_sizes, int n_in,
                              void* d_out, int out_size, void* d_ws, size_t ws_size,
                              hipStream_t stream) {
  const float* A = (const float*)d_in[0];
  // d_in[1..3] (GTConv weights) are mathematically irrelevant:
  // softmax over a singleton axis == 1.0, so each conv output is exactly 2*A.
  float* out = (float*)d_out;
  char* ws = (char*)d_ws;
  u16* Ab = (u16*)(ws);                              // 8 MB bf16 A row-major
  u16* Abt = (u16*)(ws + (size_t)N * N * 2);         // 8 MB bf16 A transposed
  u16* Mb = (u16*)(ws + (size_t)N * N * 4);          // 8 MB bf16 M = A@A
  float* rdeg = (float*)(ws + (size_t)N * N * 6);    // 8 KB reciprocal degrees

  cast_tr<<<dim3(N / 32, N / 32), dim3(32, 8), 0, stream>>>(A, Ab, Abt);
  gemm_aa<<<dim3(N / TILE, N / TILE), 256, 0, stream>>>(Ab, Abt, Mb);
  rowsum_k<<<N, 256, 0, stream>>>(Mb, rdeg);
  gemm_ma<<<dim3(N / TILE, N / TILE), 256, 0, stream>>>(Mb, Abt, A, rdeg, out);
}